// Round 8
// baseline (74.800 us; speedup 1.0000x reference)
//
#include <hip/hip_runtime.h>

// Problem: B=4, L=256, D=768, OUT=256
//   out[b,i,j,o] = pi[b,i,o] + pj[b,j,o] + bias[o]
// out: 268 MB f32 -> write-BW bound (~40 us floor at fill's 6.9 TB/s).
//
// R8: (a) gemv back to R2 form: 256 blocks x 1024 thr x 8 rows -> WT L2
//     traffic 201MB (R4's 512-block form = 402MB ~= 12us; VALU floor 5.1us).
//     16 waves/CU keeps TLP (R6's 4-wave variant was latency-bound).
// (b) bcast v6 "fill-mimic": 256 blocks (1/CU, fill runs ~215), each WAVE
//     owns one full out row = 256KB sequential stream (fill-style long runs;
//     R7's 64KB/wave was the longest tested, neutral). unroll 16 covers
//     L2 load latency at 1 wave/SIMD.
//
// ws layout (floats):
//   WT  [768][512]      : WT[d][h*256+o] = weight[o][h*768+d]   (393216 floats)
//   P   [2][1024][256]  : P[0]=pj, P[1]=pi+bias                 (524288 floats)

#define DDIM 768
#define WT_FLOATS (768 * 512)
#define P_HALF (1024 * 256)

typedef float f4 __attribute__((ext_vector_type(4)));

// ---- tiled weight transpose: weight[256][1536] -> WT[768][512] ----
__global__ __launch_bounds__(256) void k_transpose(const float* __restrict__ W,
                                                   float* __restrict__ WT) {
    __shared__ float t[32][33];
    const int c0 = blockIdx.x * 32;
    const int o0 = blockIdx.y * 32;
    const int tx = threadIdx.x & 31, ty = threadIdx.x >> 5;
#pragma unroll
    for (int yy = ty; yy < 32; yy += 8)
        t[yy][tx] = W[(size_t)(o0 + yy) * 1536 + c0 + tx];
    __syncthreads();
#pragma unroll
    for (int yy = ty; yy < 32; yy += 8) {
        int c = c0 + yy;
        int h = (c >= 768) ? 1 : 0;
        int d = c - h * 768;
        WT[(size_t)d * 512 + h * 256 + o0 + tx] = t[tx][yy];
    }
}

// ---- P computation (R2 form): 8 rows/block, 4-way d-split, 1024 threads ----
// grid (128, 2) = 256 blocks -> per-block WT read 786KB, total 201MB L2.
__global__ __launch_bounds__(1024) void k_gemv(const float* __restrict__ text,
                                               const float* __restrict__ bias,
                                               const float* __restrict__ WT,
                                               float* __restrict__ P) {
    __shared__ float red[4][8][256];   // 32 KB
    const int m0 = blockIdx.x * 8;
    const int h  = blockIdx.y;
    const int o  = threadIdx.x & 255;
    const int dg = __builtin_amdgcn_readfirstlane(threadIdx.x >> 8); // wave-uniform
    float acc[8];
#pragma unroll
    for (int r = 0; r < 8; ++r) acc[r] = 0.0f;
    const float* t0 = text + (size_t)m0 * DDIM + dg * 192;   // block+wave-uniform rows
    const float* wt = WT + (size_t)(dg * 192) * 512 + h * 256 + o;
#pragma unroll 8
    for (int d = 0; d < 192; ++d) {
        float w = wt[(size_t)d * 512];                       // coalesced across o, L2-hit
#pragma unroll
        for (int r = 0; r < 8; ++r)
            acc[r] = fmaf(t0[(size_t)r * DDIM + d], w, acc[r]);  // uniform -> scalar
    }
#pragma unroll
    for (int r = 0; r < 8; ++r) red[dg][r][o] = acc[r];
    __syncthreads();
#pragma unroll
    for (int k = 0; k < 2; ++k) {
        int flat = k * 1024 + threadIdx.x;
        int r = flat >> 8, oo = flat & 255;
        float s = red[0][r][oo] + red[1][r][oo] + red[2][r][oo] + red[3][r][oo];
        if (h) s += bias[oo];                                // fold bias into pi half
        P[(size_t)h * P_HALF + (size_t)(m0 + r) * 256 + oo] = s;
    }
}

// ---- broadcast add v6: fill-mimic long streams ----
// grid 256 (1 block/CU), 256 thr = 4 waves. Wave w owns out row r = 4*bid+w:
// 256KB written sequentially (j = 0..255, 1KB/iter). Thread: o4 fixed.
__global__ __launch_bounds__(256) void k_bcast(const float* __restrict__ P,
                                               float* __restrict__ out) {
    const int w  = threadIdx.x >> 6;                 // wave id 0..3
    const int r  = blockIdx.x * 4 + w;               // output row 0..1023
    const int b  = r >> 8;
    const int o4 = (threadIdx.x & 63) * 4;
    const f4 pi4 = *(const f4*)(P + (size_t)P_HALF + (size_t)r * 256 + o4);
    const float* pjb = P + (size_t)b * 65536 + o4;   // pj[b*256 + j][o4]
    float* outr = out + (size_t)r * 65536 + o4;
#pragma unroll 16
    for (int j = 0; j < 256; ++j) {
        f4 pj4 = *(const f4*)(pjb + (size_t)j * 256);    // L2-resident
        f4 v = pi4 + pj4;
        *(f4*)(outr + (size_t)j * 256) = v;              // sequential 1KB/wave/iter
    }
}

extern "C" void kernel_launch(void* const* d_in, const int* in_sizes, int n_in,
                              void* d_out, int out_size, void* d_ws, size_t ws_size,
                              hipStream_t stream) {
    const float* text   = (const float*)d_in[0];   // [4][256][768]
    const float* weight = (const float*)d_in[1];   // [256][1536]
    const float* bias   = (const float*)d_in[2];   // [256]
    float* out = (float*)d_out;                    // [4][256][256][256]
    float* WT  = (float*)d_ws;                     // [768][512]
    float* P   = WT + WT_FLOATS;                   // [2][1024][256]

    k_transpose<<<dim3(48, 8), 256, 0, stream>>>(weight, WT);
    k_gemv<<<dim3(128, 2), 1024, 0, stream>>>(text, bias, WT, P);
    k_bcast<<<256, 256, 0, stream>>>(P, out);
}

// Round 9
// 73.722 us; speedup vs baseline: 1.0146x; 1.0146x over previous
//
#include <hip/hip_runtime.h>

// Problem: B=4, L=256, D=768, OUT=256
//   out[b,i,j,o] = pi[b,i,o] + pj[b,j,o] + bias[o]
// out: 268 MB f32 -> write-BW bound (~40 us floor at fill's 6.9 TB/s; ~52us
// observed structural for read+write bcast).
//
// R9: clean pairing of best-known components.
//   gemv  = R2 form: 256 blocks x 1024 thr x 8 rows -> 201MB WT L2 traffic
//           (~6us, at VALU floor), 16 waves/CU.
//   bcast = R4 form verbatim (2048 blocks, j-step-4, plain stores) — the
//           only form that hit 69.8; all geometry variants since were
//           neutral-or-worse (R5 tile, R7 wave-seq, R8 fill-mimic).
//
// ws layout (floats):
//   WT  [768][512]      : WT[d][h*256+o] = weight[o][h*768+d]   (393216 floats)
//   P   [2][1024][256]  : P[0]=pj, P[1]=pi+bias                 (524288 floats)

#define DDIM 768
#define WT_FLOATS (768 * 512)
#define P_HALF (1024 * 256)

typedef float f4 __attribute__((ext_vector_type(4)));

// ---- tiled weight transpose: weight[256][1536] -> WT[768][512] ----
__global__ __launch_bounds__(256) void k_transpose(const float* __restrict__ W,
                                                   float* __restrict__ WT) {
    __shared__ float t[32][33];
    const int c0 = blockIdx.x * 32;
    const int o0 = blockIdx.y * 32;
    const int tx = threadIdx.x & 31, ty = threadIdx.x >> 5;
#pragma unroll
    for (int yy = ty; yy < 32; yy += 8)
        t[yy][tx] = W[(size_t)(o0 + yy) * 1536 + c0 + tx];
    __syncthreads();
#pragma unroll
    for (int yy = ty; yy < 32; yy += 8) {
        int c = c0 + yy;
        int h = (c >= 768) ? 1 : 0;
        int d = c - h * 768;
        WT[(size_t)d * 512 + h * 256 + o0 + tx] = t[tx][yy];
    }
}

// ---- P computation (R2 form): 8 rows/block, 4-way d-split, 1024 threads ----
// grid (128, 2) = 256 blocks -> per-block WT read 786KB, total 201MB L2 (~6us).
__global__ __launch_bounds__(1024) void k_gemv(const float* __restrict__ text,
                                               const float* __restrict__ bias,
                                               const float* __restrict__ WT,
                                               float* __restrict__ P) {
    __shared__ float red[4][8][256];   // 32 KB
    const int m0 = blockIdx.x * 8;
    const int h  = blockIdx.y;
    const int o  = threadIdx.x & 255;
    const int dg = __builtin_amdgcn_readfirstlane(threadIdx.x >> 8); // wave-uniform
    float acc[8];
#pragma unroll
    for (int r = 0; r < 8; ++r) acc[r] = 0.0f;
    const float* t0 = text + (size_t)m0 * DDIM + dg * 192;   // block+wave-uniform rows
    const float* wt = WT + (size_t)(dg * 192) * 512 + h * 256 + o;
#pragma unroll 8
    for (int d = 0; d < 192; ++d) {
        float w = wt[(size_t)d * 512];                       // coalesced across o, L2-hit
#pragma unroll
        for (int r = 0; r < 8; ++r)
            acc[r] = fmaf(t0[(size_t)r * DDIM + d], w, acc[r]);  // uniform -> scalar
    }
#pragma unroll
    for (int r = 0; r < 8; ++r) red[dg][r][o] = acc[r];
    __syncthreads();
#pragma unroll
    for (int k = 0; k < 2; ++k) {
        int flat = k * 1024 + threadIdx.x;
        int r = flat >> 8, oo = flat & 255;
        float s = red[0][r][oo] + red[1][r][oo] + red[2][r][oo] + red[3][r][oo];
        if (h) s += bias[oo];                                // fold bias into pi half
        P[(size_t)h * P_HALF + (size_t)(m0 + r) * 256 + oo] = s;
    }
}

// ---- broadcast add (R4 form): 2048 blocks, j-step-4, plain stores ----
__global__ __launch_bounds__(256) void k_bcast(const float* __restrict__ P,
                                               float* __restrict__ out) {
    const int bid  = blockIdx.x;
    const int r    = bid >> 1;
    const int half = bid & 1;
    const int b    = r >> 8;
    const int o4 = (threadIdx.x & 63) * 4;
    const int jg = threadIdx.x >> 6;
    const f4 pi4 = *(const f4*)(P + (size_t)P_HALF + (size_t)r * 256 + o4);
    const float* pjb = P + (size_t)b * 65536;        // pj[b*256 + j][o]
    float* outr = out + (size_t)r * 65536;
    const int j0 = half * 128 + jg;
#pragma unroll 8
    for (int j = j0; j < j0 + 128 - jg; j += 4) {
        f4 pj4 = *(const f4*)(pjb + j * 256 + o4);   // L2-resident
        f4 v = pi4 + pj4;
        *(f4*)(outr + j * 256 + o4) = v;             // plain store, 1KB/wave
    }
}

extern "C" void kernel_launch(void* const* d_in, const int* in_sizes, int n_in,
                              void* d_out, int out_size, void* d_ws, size_t ws_size,
                              hipStream_t stream) {
    const float* text   = (const float*)d_in[0];   // [4][256][768]
    const float* weight = (const float*)d_in[1];   // [256][1536]
    const float* bias   = (const float*)d_in[2];   // [256]
    float* out = (float*)d_out;                    // [4][256][256][256]
    float* WT  = (float*)d_ws;                     // [768][512]
    float* P   = WT + WT_FLOATS;                   // [2][1024][256]

    k_transpose<<<dim3(48, 8), 256, 0, stream>>>(weight, WT);
    k_gemv<<<dim3(128, 2), 1024, 0, stream>>>(text, bias, WT, P);
    k_bcast<<<2048, 256, 0, stream>>>(P, out);
}

// Round 10
// 56.692 us; speedup vs baseline: 1.3194x; 1.3004x over previous
//
#include <hip/hip_runtime.h>

// Problem: B=4, L=256, D=768, OUT=256
//   out[b,i,j,o] = pi[b,i,o] + pj[b,j,o] + bias[o]
// out: 268 MB f32 -> write-BW bound. bcast ~52us structural (6 probes).
//
// R10: replace transpose+f32-gemv (~12us, TCP-bound: 786KB/block through
// 64B/cyc/CU L1 path) with bf16 MFMA path:
//   k_prep: text/weight -> bf16 fragments in MFMA lane order (~1.5us)
//   k_mfma: 2048 waves x one 16x16 C-tile, no LDS, no syncs (~2us)
//   k_bcast: R4 verbatim (proven best).
// Fragment layout assumption (v_mfma_f32_16x16x32_bf16):
//   A/B: lane l elem e <-> k = (e>>2)*16 + (l>>4)*4 + (e&3), row/col = l&15
//   C/D: col = l&15, row = (l>>4)*4 + reg   [m89-verified]
//
// ws layout: P f32[2][1024][256] | Afrag bf16[64*24*64*8] | Bfrag bf16[32*24*64*8]

#define DDIM 768
#define P_HALF (1024 * 256)
#define KS 24              // K-steps of 32
#define MT 64              // 16-row A tiles (M=1024)
#define NT 32              // 16-col B tiles (N=512)

typedef float f4 __attribute__((ext_vector_type(4)));
typedef __bf16 bf16;
typedef bf16 bf16x8 __attribute__((ext_vector_type(8)));

// ---- prep: build A/B bf16 fragment arrays ----
// grid 576 x 256. bid<384: A-job (1536 lane-groups); else B-job (768 groups).
// Afrag[(mt*KS+ks)*64 + l][e] = text[mt*16 + (l&15)][ks*32 + klocal(e,l)]
// Bfrag[(nt*KS+ks)*64 + l][e] = B[k][n]: n<256 -> weight[n][k]; else weight[n-256][768+k]
__global__ __launch_bounds__(256) void k_prep(const float* __restrict__ text,
                                              const float* __restrict__ W,
                                              bf16* __restrict__ Af,
                                              bf16* __restrict__ Bf) {
    const int l = threadIdx.x & 63;
    const int kb = (l >> 4) * 4;            // k sub-base within 32
    if (blockIdx.x < 384) {
        const int g  = blockIdx.x * 4 + (threadIdx.x >> 6);   // 0..1535
        const int mt = g / KS, ks = g % KS;
        const int row = mt * 16 + (l & 15);
        const float* src = text + (size_t)row * DDIM + ks * 32 + kb;
        f4 lo = *(const f4*)(src);
        f4 hi = *(const f4*)(src + 16);
        bf16x8 v;
#pragma unroll
        for (int e = 0; e < 4; ++e) { v[e] = (bf16)lo[e]; v[e + 4] = (bf16)hi[e]; }
        *(bf16x8*)(Af + ((size_t)g * 64 + l) * 8) = v;
    } else {
        const int g  = (blockIdx.x - 384) * 4 + (threadIdx.x >> 6);  // 0..767
        const int nt = g / KS, ks = g % KS;
        const int n  = nt * 16 + (l & 15);
        const int r  = (n < 256) ? n : (n - 256);
        const int kc = (n < 256) ? 0 : DDIM;
        const float* src = W + (size_t)r * 1536 + kc + ks * 32 + kb;
        f4 lo = *(const f4*)(src);
        f4 hi = *(const f4*)(src + 16);
        bf16x8 v;
#pragma unroll
        for (int e = 0; e < 4; ++e) { v[e] = (bf16)lo[e]; v[e + 4] = (bf16)hi[e]; }
        *(bf16x8*)(Bf + ((size_t)g * 64 + l) * 8) = v;
    }
}

// ---- MFMA GEMM: C[1024][512] = A x B, bias folded into pi half ----
// 512 blocks x 256 thr = 2048 waves; wave wid: mt = wid&63, nt = wid>>6.
// Per kstep: 2 coalesced b128 loads (lane-contiguous) + 1 MFMA. No LDS.
__global__ __launch_bounds__(256) void k_mfma(const bf16* __restrict__ Af,
                                              const bf16* __restrict__ Bf,
                                              const float* __restrict__ bias,
                                              float* __restrict__ P) {
    const int l   = threadIdx.x & 63;
    const int wid = blockIdx.x * 4 + (threadIdx.x >> 6);
    const int mt  = wid & 63;
    const int nt  = wid >> 6;
    const bf16x8* ap = (const bf16x8*)Af + (size_t)(mt * KS) * 64 + l;
    const bf16x8* bp = (const bf16x8*)Bf + (size_t)(nt * KS) * 64 + l;
    f4 acc = (f4)0.0f;
#pragma unroll 6
    for (int ks = 0; ks < KS; ++ks) {
        bf16x8 a = ap[ks * 64];
        bf16x8 b = bp[ks * 64];
        acc = __builtin_amdgcn_mfma_f32_16x16x32_bf16(a, b, acc, 0, 0, 0);
    }
    const int n    = nt * 16 + (l & 15);
    const int rb   = mt * 16 + (l >> 4) * 4;
    if (n < 256) {                           // pj half
        float* p = P + (size_t)rb * 256 + n;
#pragma unroll
        for (int r = 0; r < 4; ++r) p[(size_t)r * 256] = acc[r];
    } else {                                 // pi half + bias
        const float bv = bias[n - 256];
        float* p = P + (size_t)P_HALF + (size_t)rb * 256 + (n - 256);
#pragma unroll
        for (int r = 0; r < 4; ++r) p[(size_t)r * 256] = acc[r] + bv;
    }
}

// ---- broadcast add (R4 form, proven): 2048 blocks, j-step-4, plain stores ----
__global__ __launch_bounds__(256) void k_bcast(const float* __restrict__ P,
                                               float* __restrict__ out) {
    const int bid  = blockIdx.x;
    const int r    = bid >> 1;
    const int half = bid & 1;
    const int b    = r >> 8;
    const int o4 = (threadIdx.x & 63) * 4;
    const int jg = threadIdx.x >> 6;
    const f4 pi4 = *(const f4*)(P + (size_t)P_HALF + (size_t)r * 256 + o4);
    const float* pjb = P + (size_t)b * 65536;        // pj[b*256 + j][o]
    float* outr = out + (size_t)r * 65536;
    const int j0 = half * 128 + jg;
#pragma unroll 8
    for (int j = j0; j < j0 + 128 - jg; j += 4) {
        f4 pj4 = *(const f4*)(pjb + j * 256 + o4);   // L2-resident
        f4 v = pi4 + pj4;
        *(f4*)(outr + j * 256 + o4) = v;             // plain store, 1KB/wave
    }
}

extern "C" void kernel_launch(void* const* d_in, const int* in_sizes, int n_in,
                              void* d_out, int out_size, void* d_ws, size_t ws_size,
                              hipStream_t stream) {
    const float* text   = (const float*)d_in[0];   // [4][256][768]
    const float* weight = (const float*)d_in[1];   // [256][1536]
    const float* bias   = (const float*)d_in[2];   // [256]
    float* out = (float*)d_out;                    // [4][256][256][256]
    float* P   = (float*)d_ws;                     // [2][1024][256] f32
    bf16* Af   = (bf16*)(P + 2 * P_HALF);          // [64*24*64*8]
    bf16* Bf   = Af + (size_t)MT * KS * 64 * 8;    // [32*24*64*8]

    k_prep<<<576, 256, 0, stream>>>(text, weight, Af, Bf);
    k_mfma<<<512, 256, 0, stream>>>(Af, Bf, bias, P);
    k_bcast<<<2048, 256, 0, stream>>>(P, out);
}